// Round 2
// baseline (194.807 us; speedup 1.0000x reference)
//
#include <hip/hip_runtime.h>
#include <hip/hip_bf16.h>

// CenterWoParamsLoss: loss = sum((x - centers[labels])^2) / 2 / BATCH
// x: (16384, 2048) fp32, labels: (16384,) int, centers: (1000, 2048) fp32.
// Pure HBM-bound streaming reduce: ~136 MiB total traffic -> ~22 us floor.

#define CL_BATCH 16384
#define CL_FEAT  2048
#define CL_F4    (CL_FEAT / 4)      // 512 float4 per row
#define CL_NBLK  2048               // partial-sum blocks
#define CL_TPB   256

__global__ __launch_bounds__(CL_TPB) void center_loss_partial_kernel(
    const float* __restrict__ x,
    const int* __restrict__ labels,
    const float* __restrict__ centers,
    float* __restrict__ partial) {
  const int total4 = CL_BATCH * CL_F4;  // 8,388,608 float4 elements
  const float4* __restrict__ x4 = reinterpret_cast<const float4*>(x);
  const float4* __restrict__ c4 = reinterpret_cast<const float4*>(centers);

  float acc = 0.0f;
  int stride = gridDim.x * blockDim.x;
  for (int f = blockIdx.x * blockDim.x + threadIdx.x; f < total4; f += stride) {
    int row  = f >> 9;        // f / 512
    int col4 = f & 511;       // f % 512
    int lab  = labels[row];   // L1/L2-resident, mostly wave-uniform
    float4 xv = x4[f];
    float4 cv = c4[lab * CL_F4 + col4];  // centers cache-resident (8 MiB)
    float dx = xv.x - cv.x;
    float dy = xv.y - cv.y;
    float dz = xv.z - cv.z;
    float dw = xv.w - cv.w;
    acc += dx * dx + dy * dy + dz * dz + dw * dw;
  }

  // wave-64 butterfly reduce
  #pragma unroll
  for (int off = 32; off > 0; off >>= 1)
    acc += __shfl_down(acc, off, 64);

  __shared__ float lds[CL_TPB / 64];
  int wave = threadIdx.x >> 6;
  int lane = threadIdx.x & 63;
  if (lane == 0) lds[wave] = acc;
  __syncthreads();
  if (threadIdx.x == 0) {
    float s = 0.0f;
    #pragma unroll
    for (int w = 0; w < CL_TPB / 64; ++w) s += lds[w];
    partial[blockIdx.x] = s;
  }
}

__global__ __launch_bounds__(CL_TPB) void center_loss_reduce_kernel(
    const float* __restrict__ partial, float* __restrict__ out) {
  float acc = 0.0f;
  for (int i = threadIdx.x; i < CL_NBLK; i += CL_TPB) acc += partial[i];
  #pragma unroll
  for (int off = 32; off > 0; off >>= 1)
    acc += __shfl_down(acc, off, 64);

  __shared__ float lds[CL_TPB / 64];
  int wave = threadIdx.x >> 6;
  int lane = threadIdx.x & 63;
  if (lane == 0) lds[wave] = acc;
  __syncthreads();
  if (threadIdx.x == 0) {
    float s = 0.0f;
    #pragma unroll
    for (int w = 0; w < CL_TPB / 64; ++w) s += lds[w];
    out[0] = s * (0.5f / (float)CL_BATCH);
  }
}

extern "C" void kernel_launch(void* const* d_in, const int* in_sizes, int n_in,
                              void* d_out, int out_size, void* d_ws, size_t ws_size,
                              hipStream_t stream) {
  const float* x       = (const float*)d_in[0];
  const int*   labels  = (const int*)d_in[1];
  const float* centers = (const float*)d_in[2];
  float* out     = (float*)d_out;
  float* partial = (float*)d_ws;   // CL_NBLK floats = 8 KiB of scratch

  center_loss_partial_kernel<<<CL_NBLK, CL_TPB, 0, stream>>>(x, labels, centers, partial);
  center_loss_reduce_kernel<<<1, CL_TPB, 0, stream>>>(partial, out);
}